// Round 1
// baseline (2017.060 us; speedup 1.0000x reference)
//
#include <hip/hip_runtime.h>
#include <cstdint>
#include <cstddef>

// Problem constants (from reference)
constexpr int Bb  = 4;
constexpr int Cc  = 2048;
constexpr int Hh  = 8;
constexpr int DK_ = 64;
constexpr int DV_ = 128;
constexpr int DIN_ = 1024;
constexpr int Mrows = Bb * Cc;   // 8192

// ---------------------------------------------------------------------------
// Generic fp32 GEMM: out[M,N] = A[M,K] @ W[N,K]^T + bias[N]
// 64x64 tile, BK=16, 256 threads, 4x4 per thread.
// ---------------------------------------------------------------------------
__global__ __launch_bounds__(256) void gemm_bias(
    const float* __restrict__ A, const float* __restrict__ W,
    const float* __restrict__ bias, float* __restrict__ outp,
    int M, int N, int K)
{
  __shared__ float As[16][68];   // [k][m], padded
  __shared__ float Ws[16][68];   // [k][n], padded
  const int t  = threadIdx.x;
  const int m0 = blockIdx.y * 64;
  const int n0 = blockIdx.x * 64;
  const int tx = t & 15, ty = t >> 4;
  const int lr = t >> 2;          // 0..63 row within tile
  const int lk = (t & 3) * 4;     // 0,4,8,12 k offset

  float acc[4][4] = {};
  const float* Arow = A + (size_t)(m0 + lr) * K + lk;
  const float* Wrow = W + (size_t)(n0 + lr) * K + lk;

  for (int k0 = 0; k0 < K; k0 += 16) {
    float4 av = *(const float4*)(Arow + k0);
    float4 wv = *(const float4*)(Wrow + k0);
    As[lk+0][lr] = av.x; As[lk+1][lr] = av.y; As[lk+2][lr] = av.z; As[lk+3][lr] = av.w;
    Ws[lk+0][lr] = wv.x; Ws[lk+1][lr] = wv.y; Ws[lk+2][lr] = wv.z; Ws[lk+3][lr] = wv.w;
    __syncthreads();
#pragma unroll
    for (int kk = 0; kk < 16; kk++) {
      float4 a4 = *(const float4*)&As[kk][ty*4];
      float4 w4 = *(const float4*)&Ws[kk][tx*4];
      float a[4] = {a4.x, a4.y, a4.z, a4.w};
      float w[4] = {w4.x, w4.y, w4.z, w4.w};
#pragma unroll
      for (int i = 0; i < 4; i++)
#pragma unroll
        for (int j = 0; j < 4; j++)
          acc[i][j] += a[i] * w[j];
    }
    __syncthreads();
  }

#pragma unroll
  for (int i = 0; i < 4; i++) {
    int m = m0 + ty*4 + i;
    float4 b4 = *(const float4*)&bias[n0 + tx*4];
    float4 o;
    o.x = acc[i][0] + b4.x; o.y = acc[i][1] + b4.y;
    o.z = acc[i][2] + b4.z; o.w = acc[i][3] + b4.w;
    *(float4*)&outp[(size_t)m * N + n0 + tx*4] = o;
  }
}

// ---------------------------------------------------------------------------
// Pass 1: invZ[bh, k] = 1 / sum_q exp((q.k + mask[b,q]) / 8)
// Softmax is over the QUERY axis (column-normalized), so we need the full
// column sum before any output can be produced.
// Q/K vectors: (b,h,c) lives at buf + bh*C*64 + c*64 (flat-reshape layout).
// grid: (C/64 k-tiles, B*H). block 256.
// ---------------------------------------------------------------------------
__global__ __launch_bounds__(256) void attn_pass1(
    const float* __restrict__ Qbuf, const float* __restrict__ Kbuf,
    const float* __restrict__ mask, float* __restrict__ invZ)
{
  __shared__ float Ks[64][68];
  __shared__ float Qs[64][68];
  __shared__ float red[16][64];
  const int t  = threadIdx.x;
  const int bh = blockIdx.y;
  const int b  = bh >> 3;
  const int kt = blockIdx.x * 64;
  const float* Kb = Kbuf + (size_t)bh * (Cc * DK_);
  const float* Qb = Qbuf + (size_t)bh * (Cc * DK_);
  const float* mrow = mask + (size_t)b * Cc;

  // load K tile (64 k-rows x 64 dims)
#pragma unroll
  for (int i = 0; i < 4; i++) {
    int fl = t + 256*i, row = fl >> 4, d0 = (fl & 15) * 4;
    *(float4*)&Ks[row][d0] = *(const float4*)&Kb[(size_t)(kt + row) * DK_ + d0];
  }

  const int tx = t & 15, ty = t >> 4;
  float zacc[4] = {0.f, 0.f, 0.f, 0.f};

  for (int qt = 0; qt < Cc; qt += 64) {
    __syncthreads();  // Qs reuse guard (also makes Ks visible on iter 0)
#pragma unroll
    for (int i = 0; i < 4; i++) {
      int fl = t + 256*i, row = fl >> 4, d0 = (fl & 15) * 4;
      *(float4*)&Qs[row][d0] = *(const float4*)&Qb[(size_t)(qt + row) * DK_ + d0];
    }
    __syncthreads();

    float dots[4][4] = {};
#pragma unroll
    for (int d = 0; d < 64; d += 4) {
      float4 q4[4], k4[4];
#pragma unroll
      for (int i = 0; i < 4; i++) q4[i] = *(const float4*)&Qs[ty*4+i][d];
#pragma unroll
      for (int j = 0; j < 4; j++) k4[j] = *(const float4*)&Ks[tx*4+j][d];
#pragma unroll
      for (int i = 0; i < 4; i++)
#pragma unroll
        for (int j = 0; j < 4; j++)
          dots[i][j] += q4[i].x*k4[j].x + q4[i].y*k4[j].y
                      + q4[i].z*k4[j].z + q4[i].w*k4[j].w;
    }
#pragma unroll
    for (int i = 0; i < 4; i++) {
      float mv = mrow[qt + ty*4 + i];
#pragma unroll
      for (int j = 0; j < 4; j++)
        zacc[j] += __expf((dots[i][j] + mv) * 0.125f);
    }
  }

  __syncthreads();
#pragma unroll
  for (int j = 0; j < 4; j++) red[ty][tx*4+j] = zacc[j];
  __syncthreads();
  if (t < 64) {
    float s = 0.f;
#pragma unroll
    for (int r = 0; r < 16; r++) s += red[r][t];
    invZ[(size_t)bh * Cc + kt + t] = 1.0f / s;
  }
}

// ---------------------------------------------------------------------------
// Pass 2: A[bh, q, :] = sum_k exp((q.k + mask[b,q])/8) * invZ[k] * V[bh,k,:]
// Recomputes the QK tile (cheaper than materializing 512 MB of scores).
// Out tile: 64 q x 128 dv; k-tile 32. grid: (C/64 q-tiles, B*H).
// Writes A at the flat [B,H,C,DV] linear index so the Wo GEMM can read it
// as [B*C, H*DV] row-major (the reference's flat reshape for free).
// ---------------------------------------------------------------------------
__global__ __launch_bounds__(256) void attn_pass2(
    const float* __restrict__ Qbuf, const float* __restrict__ Kbuf,
    const float* __restrict__ Vbuf, const float* __restrict__ mask,
    const float* __restrict__ invZ, float* __restrict__ Abuf)
{
  __shared__ float Qs[64][68];
  __shared__ float Ks[32][68];
  __shared__ float Ps[64][36];    // P'[q][k] = exp(s)*invZ[k]
  __shared__ float Vs[32][132];
  __shared__ float ms[64];

  const int t  = threadIdx.x;
  const int bh = blockIdx.y;
  const int b  = bh >> 3;
  const int qt = blockIdx.x * 64;
  const float* Qb = Qbuf + (size_t)bh * (Cc * DK_);
  const float* Kb = Kbuf + (size_t)bh * (Cc * DK_);
  const float* Vb = Vbuf + (size_t)bh * (size_t)(Cc * DV_);
  const float* iZ = invZ + (size_t)bh * Cc;

  // Q tile (reused for all k-tiles)
#pragma unroll
  for (int i = 0; i < 4; i++) {
    int fl = t + 256*i, row = fl >> 4, d0 = (fl & 15) * 4;
    *(float4*)&Qs[row][d0] = *(const float4*)&Qb[(size_t)(qt + row) * DK_ + d0];
  }
  if (t < 64) ms[t] = mask[(size_t)b * Cc + qt + t];

  const int pty = t >> 3;   // 0..31 -> q pair base pty*2
  const int ptx = t & 7;    // 0..7  -> k group ptx*4
  const int ty2 = t >> 5;   // 0..7  -> q group ty2*8
  const int tx2 = t & 31;   // 0..31 -> dv group tx2*4

  float acc[8][4] = {};

  for (int k0 = 0; k0 < Cc; k0 += 32) {
    __syncthreads();  // Ks/Vs/Ps reuse guard (also Qs/ms visibility on iter 0)
    // K tile 32x64
#pragma unroll
    for (int i = 0; i < 2; i++) {
      int fl = t + 256*i, row = fl >> 4, d0 = (fl & 15) * 4;
      *(float4*)&Ks[row][d0] = *(const float4*)&Kb[(size_t)(k0 + row) * DK_ + d0];
    }
    // V tile 32x128
#pragma unroll
    for (int i = 0; i < 4; i++) {
      int fl = t + 256*i, row = fl >> 5, d0 = (fl & 31) * 4;
      *(float4*)&Vs[row][d0] = *(const float4*)&Vb[(size_t)(k0 + row) * DV_ + d0];
    }
    __syncthreads();

    // P stage: 2 q x 4 k dots per thread
    float dots[2][4] = {};
#pragma unroll
    for (int d = 0; d < 64; d += 4) {
      float4 q4[2], k4[4];
      q4[0] = *(const float4*)&Qs[pty*2+0][d];
      q4[1] = *(const float4*)&Qs[pty*2+1][d];
#pragma unroll
      for (int j = 0; j < 4; j++) k4[j] = *(const float4*)&Ks[ptx*4+j][d];
#pragma unroll
      for (int i = 0; i < 2; i++)
#pragma unroll
        for (int j = 0; j < 4; j++)
          dots[i][j] += q4[i].x*k4[j].x + q4[i].y*k4[j].y
                      + q4[i].z*k4[j].z + q4[i].w*k4[j].w;
    }
#pragma unroll
    for (int i = 0; i < 2; i++) {
      float mv = ms[pty*2+i];
#pragma unroll
      for (int j = 0; j < 4; j++)
        Ps[pty*2+i][ptx*4+j] = __expf((dots[i][j] + mv) * 0.125f) * iZ[k0 + ptx*4 + j];
    }
    __syncthreads();

    // PV stage: acc[8 q][4 dv]
#pragma unroll
    for (int kk = 0; kk < 32; kk++) {
      float4 v4 = *(const float4*)&Vs[kk][tx2*4];
#pragma unroll
      for (int i = 0; i < 8; i++) {
        float p = Ps[ty2*8+i][kk];
        acc[i][0] += p * v4.x; acc[i][1] += p * v4.y;
        acc[i][2] += p * v4.z; acc[i][3] += p * v4.w;
      }
    }
  }

  // epilogue: write at flat [B,H,C,DV] linear index
#pragma unroll
  for (int i = 0; i < 8; i++) {
    int q = ty2*8 + i;
    float4 o = {acc[i][0], acc[i][1], acc[i][2], acc[i][3]};
    *(float4*)&Abuf[((size_t)bh * Cc + qt + q) * DV_ + tx2*4] = o;
  }
}

// ---------------------------------------------------------------------------
extern "C" void kernel_launch(void* const* d_in, const int* in_sizes, int n_in,
                              void* d_out, int out_size, void* d_ws, size_t ws_size,
                              hipStream_t stream)
{
  const float* x    = (const float*)d_in[0];
  const float* mask = (const float*)d_in[1];
  const float* Mq_w = (const float*)d_in[2];
  const float* Mq_b = (const float*)d_in[3];
  const float* Mk_w = (const float*)d_in[4];
  const float* Mk_b = (const float*)d_in[5];
  const float* Mv_w = (const float*)d_in[6];
  const float* Mv_b = (const float*)d_in[7];
  const float* Wo_w = (const float*)d_in[8];
  const float* Wo_b = (const float*)d_in[9];
  float* outp = (float*)d_out;

  // workspace layout (fp32): Q[8192,512] K[8192,512] V[8192,1024] A[8192,1024] invZ[32*2048]
  float* Qbuf = (float*)d_ws;
  float* Kbuf = Qbuf + (size_t)Mrows * 512;
  float* Vbuf = Kbuf + (size_t)Mrows * 512;
  float* Abuf = Vbuf + (size_t)Mrows * 1024;
  float* invZ = Abuf + (size_t)Mrows * 1024;

  dim3 blk(256);
  // projections
  gemm_bias<<<dim3(512/64,  Mrows/64), blk, 0, stream>>>(x, Mq_w, Mq_b, Qbuf, Mrows, 512, 1024);
  gemm_bias<<<dim3(512/64,  Mrows/64), blk, 0, stream>>>(x, Mk_w, Mk_b, Kbuf, Mrows, 512, 1024);
  gemm_bias<<<dim3(1024/64, Mrows/64), blk, 0, stream>>>(x, Mv_w, Mv_b, Vbuf, Mrows, 1024, 1024);
  // column-softmax attention, two passes
  attn_pass1<<<dim3(Cc/64, Bb*Hh), blk, 0, stream>>>(Qbuf, Kbuf, mask, invZ);
  attn_pass2<<<dim3(Cc/64, Bb*Hh), blk, 0, stream>>>(Qbuf, Kbuf, Vbuf, mask, invZ, Abuf);
  // output projection
  gemm_bias<<<dim3(1024/64, Mrows/64), blk, 0, stream>>>(Abuf, Wo_w, Wo_b, outp, Mrows, 1024, 1024);
}

// Round 2
// 584.814 us; speedup vs baseline: 3.4491x; 3.4491x over previous
//
#include <hip/hip_runtime.h>
#include <cstdint>
#include <cstddef>

// Problem constants
constexpr int Cc = 2048;         // sequence length
constexpr int Mrows = 8192;      // B*C

typedef __attribute__((ext_vector_type(8))) short short8;
typedef __attribute__((ext_vector_type(4))) float floatx4;

#define MFMA_BF16(a, b, c) __builtin_amdgcn_mfma_f32_16x16x32_bf16((a), (b), (c), 0, 0, 0)

__device__ __forceinline__ unsigned short f2bf(float f) {
  union { float f; unsigned u; } v; v.f = f;
  unsigned r = v.u + 0x7fffu + ((v.u >> 16) & 1u);   // RNE
  return (unsigned short)(r >> 16);
}

// ---------------------------------------------------------------------------
// Cast x + 4 weight matrices fp32 -> bf16, one launch, 8 elems/thread.
// Segment sizes are compile-time constants.
// ---------------------------------------------------------------------------
__global__ __launch_bounds__(256) void cast_all(
    const float* __restrict__ x,  const float* __restrict__ mq,
    const float* __restrict__ mk, const float* __restrict__ mv,
    const float* __restrict__ wo,
    unsigned short* __restrict__ xb,  unsigned short* __restrict__ wqb,
    unsigned short* __restrict__ wkb, unsigned short* __restrict__ wvb,
    unsigned short* __restrict__ wob)
{
  size_t i = ((size_t)blockIdx.x * 256 + threadIdx.x) * 8;
  const float* src; unsigned short* dst; size_t j;
  if      (i <  8388608) { src = x;  dst = xb;  j = i; }
  else if (i <  8912896) { src = mq; dst = wqb; j = i -  8388608; }
  else if (i <  9437184) { src = mk; dst = wkb; j = i -  8912896; }
  else if (i < 10485760) { src = mv; dst = wvb; j = i -  9437184; }
  else if (i < 11534336) { src = wo; dst = wob; j = i - 10485760; }
  else return;
  float4 a = *(const float4*)(src + j);
  float4 b = *(const float4*)(src + j + 4);
  short8 o;
  o[0] = (short)f2bf(a.x); o[1] = (short)f2bf(a.y);
  o[2] = (short)f2bf(a.z); o[3] = (short)f2bf(a.w);
  o[4] = (short)f2bf(b.x); o[5] = (short)f2bf(b.y);
  o[6] = (short)f2bf(b.z); o[7] = (short)f2bf(b.w);
  *(short8*)(dst + j) = o;
}

// ---------------------------------------------------------------------------
// bf16 MFMA GEMM: out[M,N] = A[M,K] @ W[N,K]^T + bias.
// 128x128 tile, BK=32, 256 thr = 4 waves (2x2 of 64x64), 16x16x32 MFMA.
// LDS staging with XOR chunk swizzle: slot s holds global chunk
// (row = s>>2, c = (s&3) ^ ((row>>1)&3)); read side inverts -> ds_read_b128
// conflict-free per 8-lane phase.
// ---------------------------------------------------------------------------
template<int OUT_BF16>
__global__ __launch_bounds__(256) void gemm_mfma(
    const unsigned short* __restrict__ A, const unsigned short* __restrict__ W,
    const float* __restrict__ bias, void* __restrict__ outp,
    int M, int N, int K)
{
  __shared__ __align__(16) unsigned short As[128 * 32];
  __shared__ __align__(16) unsigned short Ws[128 * 32];
  const int t    = threadIdx.x;
  const int lane = t & 63, wid = t >> 6;
  const int wr = wid >> 1, wc = wid & 1;
  const int quad = lane >> 4, l15 = lane & 15;
  const int m0 = blockIdx.y * 128, n0 = blockIdx.x * 128;

  // staging slots t and t+256
  const int s1   = t + 256;
  const int row0 = t >> 2,  c0 = (t & 3)  ^ ((row0 >> 1) & 3);
  const int row1 = s1 >> 2, c1 = (s1 & 3) ^ ((row1 >> 1) & 3);
  const unsigned short* gA0 = A + (size_t)(m0 + row0) * K + c0 * 8;
  const unsigned short* gA1 = A + (size_t)(m0 + row1) * K + c1 * 8;
  const unsigned short* gB0 = W + (size_t)(n0 + row0) * K + c0 * 8;
  const unsigned short* gB1 = W + (size_t)(n0 + row1) * K + c1 * 8;

  int offA[4], offB[4];
#pragma unroll
  for (int f = 0; f < 4; f++) {
    int ra = wr * 64 + f * 16 + l15;
    offA[f] = (ra * 4 + (quad ^ ((ra >> 1) & 3))) * 8;   // in shorts
    int rb = wc * 64 + f * 16 + l15;
    offB[f] = (rb * 4 + (quad ^ ((rb >> 1) & 3))) * 8;
  }

  floatx4 acc[4][4];
#pragma unroll
  for (int i = 0; i < 4; i++)
#pragma unroll
    for (int j = 0; j < 4; j++) acc[i][j] = (floatx4){0.f, 0.f, 0.f, 0.f};

  float4 ra0 = *(const float4*)gA0;
  float4 ra1 = *(const float4*)gA1;
  float4 rb0 = *(const float4*)gB0;
  float4 rb1 = *(const float4*)gB1;

  for (int k0 = 0; k0 < K; k0 += 32) {
    __syncthreads();
    *(float4*)&As[(size_t)t  * 8] = ra0;
    *(float4*)&As[(size_t)s1 * 8] = ra1;
    *(float4*)&Ws[(size_t)t  * 8] = rb0;
    *(float4*)&Ws[(size_t)s1 * 8] = rb1;
    __syncthreads();
    if (k0 + 32 < K) {          // prefetch next tile, overlaps MFMA below
      gA0 += 32; gA1 += 32; gB0 += 32; gB1 += 32;
      ra0 = *(const float4*)gA0; ra1 = *(const float4*)gA1;
      rb0 = *(const float4*)gB0; rb1 = *(const float4*)gB1;
    }
    short8 aF[4], bF[4];
#pragma unroll
    for (int f = 0; f < 4; f++) {
      aF[f] = *(const short8*)&As[offA[f]];
      bF[f] = *(const short8*)&Ws[offB[f]];
    }
#pragma unroll
    for (int i = 0; i < 4; i++)
#pragma unroll
      for (int j = 0; j < 4; j++)
        acc[i][j] = MFMA_BF16(aF[i], bF[j], acc[i][j]);
  }

#pragma unroll
  for (int fn = 0; fn < 4; fn++) {
    int col = n0 + wc * 64 + fn * 16 + l15;
    float bv = bias[col];
#pragma unroll
    for (int fm = 0; fm < 4; fm++) {
#pragma unroll
      for (int r = 0; r < 4; r++) {
        int m = m0 + wr * 64 + fm * 16 + quad * 4 + r;
        float v = acc[fm][fn][r] + bv;
        if (OUT_BF16)
          ((unsigned short*)outp)[(size_t)m * N + col] = f2bf(v);
        else
          ((float*)outp)[(size_t)m * N + col] = v;
      }
    }
  }
}

// ---------------------------------------------------------------------------
// Transpose V[bh][c][128] -> VT[bh][dv][2048] (bf16), 32-c tiles.
// ---------------------------------------------------------------------------
__global__ __launch_bounds__(256) void transpose_v(
    const unsigned short* __restrict__ V, unsigned short* __restrict__ VT)
{
  __shared__ __align__(16) unsigned short Vs[32][136];
  const int bh = blockIdx.y, ct = blockIdx.x * 32;
  const int t = threadIdx.x;
  const unsigned short* Vb  = V  + (size_t)bh * Cc * 128;
  unsigned short*       VTb = VT + (size_t)bh * 128 * Cc;
#pragma unroll
  for (int i = 0; i < 2; i++) {
    int idx = t + i * 256, c = idx >> 4, d0 = (idx & 15) * 8;
    *(short8*)&Vs[c][d0] = *(const short8*)(Vb + (size_t)(ct + c) * 128 + d0);
  }
  __syncthreads();
#pragma unroll
  for (int i = 0; i < 2; i++) {
    int idx = t + i * 256, dv = idx >> 2, cb = (idx & 3) * 8;
    short8 o;
#pragma unroll
    for (int j = 0; j < 8; j++) o[j] = (short)Vs[cb + j][dv];
    *(short8*)(VTb + (size_t)dv * Cc + ct + cb) = o;
  }
}

// ---------------------------------------------------------------------------
// Pass 1: invZ[bh,k] = 1 / sum_q exp((q.k + mask[b,q])/8)   (softmax over q)
// Block = (k-tile of 64) x bh. K-frags live in registers; Q streamed from
// global (L2-resident). No LDS except the final 4-wave reduce.
// ---------------------------------------------------------------------------
__global__ __launch_bounds__(256) void attn_pass1(
    const unsigned short* __restrict__ Q_, const unsigned short* __restrict__ K_,
    const float* __restrict__ mask, float* __restrict__ invZ)
{
  const int t = threadIdx.x, lane = t & 63, wid = t >> 6;
  const int quad = lane >> 4, l15 = lane & 15;
  const int bh = blockIdx.y, b = bh >> 3;
  const int kt = blockIdx.x * 64;
  const unsigned short* Kb = K_ + (size_t)bh * Cc * 64;
  const unsigned short* Qb = Q_ + (size_t)bh * Cc * 64;
  const float* mrow = mask + (size_t)b * Cc;

  short8 kF[4][2];
#pragma unroll
  for (int kf = 0; kf < 4; kf++)
#pragma unroll
    for (int s = 0; s < 2; s++)
      kF[kf][s] = *(const short8*)(Kb + (size_t)(kt + kf * 16 + l15) * 64 + s * 32 + quad * 8);

  float zacc[4] = {0.f, 0.f, 0.f, 0.f};

  for (int qt = wid * 16; qt < Cc; qt += 64) {
    short8 qa[2];
#pragma unroll
    for (int s = 0; s < 2; s++)
      qa[s] = *(const short8*)(Qb + (size_t)(qt + l15) * 64 + s * 32 + quad * 8);
    float4 mv = *(const float4*)(mrow + qt + quad * 4);
#pragma unroll
    for (int kf = 0; kf < 4; kf++) {
      floatx4 d = (floatx4){0.f, 0.f, 0.f, 0.f};
      d = MFMA_BF16(qa[0], kF[kf][0], d);
      d = MFMA_BF16(qa[1], kF[kf][1], d);
      zacc[kf] += __expf((d[0] + mv.x) * 0.125f) + __expf((d[1] + mv.y) * 0.125f)
                + __expf((d[2] + mv.z) * 0.125f) + __expf((d[3] + mv.w) * 0.125f);
    }
  }

  __shared__ float red[4][64];
#pragma unroll
  for (int kf = 0; kf < 4; kf++) {
    float v = zacc[kf];
    v += __shfl_xor(v, 16);
    v += __shfl_xor(v, 32);
    if (lane < 16) red[wid][kf * 16 + lane] = v;
  }
  __syncthreads();
  if (t < 64) {
    float z = red[0][t] + red[1][t] + red[2][t] + red[3][t];
    invZ[(size_t)bh * Cc + kt + t] = 1.0f / z;
  }
}

// ---------------------------------------------------------------------------
// Pass 2: A[bh,q,:] = sum_k exp((q.k+mask)/8)*invZ[k]*V[k,:], MFMA both stages.
// Block = (q-tile 64) x bh; wave handles 16 q rows x all 128 dv.
// P goes C-layout -> LDS (stride 40 shorts) -> A-layout for the PV MFMA.
// ---------------------------------------------------------------------------
__global__ __launch_bounds__(256) void attn_pass2(
    const unsigned short* __restrict__ Q_, const unsigned short* __restrict__ K_,
    const unsigned short* __restrict__ VT_, const float* __restrict__ mask,
    const float* __restrict__ invZ, unsigned short* __restrict__ Ab)
{
  __shared__ __align__(16) unsigned short Ps[64 * 40];
  const int t = threadIdx.x, lane = t & 63, wid = t >> 6;
  const int quad = lane >> 4, l15 = lane & 15;
  const int bh = blockIdx.y, b = bh >> 3;
  const int qt = blockIdx.x * 64;
  const unsigned short* Qb = Q_  + (size_t)bh * Cc * 64;
  const unsigned short* Kb = K_  + (size_t)bh * Cc * 64;
  const unsigned short* VTb = VT_ + (size_t)bh * 128 * Cc;
  const float* iZ = invZ + (size_t)bh * Cc;

  short8 qa[2];
#pragma unroll
  for (int s = 0; s < 2; s++)
    qa[s] = *(const short8*)(Qb + (size_t)(qt + wid * 16 + l15) * 64 + s * 32 + quad * 8);
  float4 mv = *(const float4*)(mask + (size_t)b * Cc + qt + wid * 16 + quad * 4);

  floatx4 acc[8];
#pragma unroll
  for (int fn = 0; fn < 8; fn++) acc[fn] = (floatx4){0.f, 0.f, 0.f, 0.f};

  for (int kb = 0; kb < Cc; kb += 32) {
    // S-tile: wave's 16 q x 32 k via MFMA from global K
    floatx4 d[2];
#pragma unroll
    for (int kf = 0; kf < 2; kf++) {
      short8 k0f = *(const short8*)(Kb + (size_t)(kb + kf * 16 + l15) * 64 + quad * 8);
      short8 k1f = *(const short8*)(Kb + (size_t)(kb + kf * 16 + l15) * 64 + 32 + quad * 8);
      floatx4 z = (floatx4){0.f, 0.f, 0.f, 0.f};
      z = MFMA_BF16(qa[0], k0f, z);
      d[kf] = MFMA_BF16(qa[1], k1f, z);
    }
    __syncthreads();   // previous iteration's Ps reads complete
#pragma unroll
    for (int kf = 0; kf < 2; kf++) {
      float iz = iZ[kb + kf * 16 + l15];
#pragma unroll
      for (int r = 0; r < 4; r++) {
        float mvr = (r == 0) ? mv.x : (r == 1) ? mv.y : (r == 2) ? mv.z : mv.w;
        float p = __expf((d[kf][r] + mvr) * 0.125f) * iz;
        Ps[(size_t)(wid * 16 + quad * 4 + r) * 40 + kf * 16 + l15] = f2bf(p);
      }
    }
    __syncthreads();
    short8 pa = *(const short8*)&Ps[(size_t)(wid * 16 + l15) * 40 + quad * 8];
#pragma unroll
    for (int fn = 0; fn < 8; fn++) {
      short8 vf = *(const short8*)(VTb + (size_t)(fn * 16 + l15) * Cc + kb + quad * 8);
      acc[fn] = MFMA_BF16(pa, vf, acc[fn]);
    }
  }

#pragma unroll
  for (int fn = 0; fn < 8; fn++) {
#pragma unroll
    for (int r = 0; r < 4; r++) {
      int q = qt + wid * 16 + quad * 4 + r;
      Ab[((size_t)bh * Cc + q) * 128 + fn * 16 + l15] = f2bf(acc[fn][r]);
    }
  }
}

// ---------------------------------------------------------------------------
extern "C" void kernel_launch(void* const* d_in, const int* in_sizes, int n_in,
                              void* d_out, int out_size, void* d_ws, size_t ws_size,
                              hipStream_t stream)
{
  const float* x    = (const float*)d_in[0];
  const float* mask = (const float*)d_in[1];
  const float* Mq_w = (const float*)d_in[2];
  const float* Mq_b = (const float*)d_in[3];
  const float* Mk_w = (const float*)d_in[4];
  const float* Mk_b = (const float*)d_in[5];
  const float* Mv_w = (const float*)d_in[6];
  const float* Mv_b = (const float*)d_in[7];
  const float* Wo_w = (const float*)d_in[8];
  const float* Wo_b = (const float*)d_in[9];
  float* outp = (float*)d_out;

  // workspace (bf16 shorts unless noted)
  unsigned short* xb  = (unsigned short*)d_ws;
  unsigned short* wq  = xb  + 8388608;     // x:       8192x1024
  unsigned short* wk  = wq  + 524288;      // Mq_w:    512x1024
  unsigned short* wv  = wk  + 524288;
  unsigned short* wo  = wv  + 1048576;     // Mv_w:    1024x1024
  unsigned short* Qb  = wo  + 1048576;     // Wo_w:    1024x1024
  unsigned short* Kb  = Qb  + 4194304;     // Q:       8192x512
  unsigned short* Vb  = Kb  + 4194304;
  unsigned short* VTb = Vb  + 8388608;     // V:       8192x1024
  unsigned short* Ab  = VTb + 8388608;     // VT:      32x128x2048
  float*          invZ = (float*)(Ab + 8388608);  // 32x2048 fp32

  dim3 blk(256);
  cast_all<<<5632, blk, 0, stream>>>(x, Mq_w, Mk_w, Mv_w, Wo_w, xb, wq, wk, wv, wo);

  gemm_mfma<1><<<dim3(4, 64), blk, 0, stream>>>(xb, wq, Mq_b, Qb, Mrows, 512, 1024);
  gemm_mfma<1><<<dim3(4, 64), blk, 0, stream>>>(xb, wk, Mk_b, Kb, Mrows, 512, 1024);
  gemm_mfma<1><<<dim3(8, 64), blk, 0, stream>>>(xb, wv, Mv_b, Vb, Mrows, 1024, 1024);

  transpose_v<<<dim3(64, 32), blk, 0, stream>>>(Vb, VTb);

  attn_pass1<<<dim3(32, 32), blk, 0, stream>>>(Qb, Kb, mask, invZ);
  attn_pass2<<<dim3(32, 32), blk, 0, stream>>>(Qb, Kb, VTb, mask, invZ, Ab);

  gemm_mfma<0><<<dim3(8, 64), blk, 0, stream>>>(Ab, wo, Wo_b, outp, Mrows, 1024, 1024);
}

// Round 3
// 317.137 us; speedup vs baseline: 6.3602x; 1.8440x over previous
//
#include <hip/hip_runtime.h>
#include <cstdint>
#include <cstddef>

constexpr int Cc = 2048;         // sequence length
constexpr int Mrows = 8192;      // B*C

typedef __attribute__((ext_vector_type(8))) short short8;
typedef __attribute__((ext_vector_type(4))) float floatx4;
typedef __attribute__((ext_vector_type(4))) unsigned short ushortx4;
typedef unsigned short us;

#define MFMA_BF16(a, b, c) __builtin_amdgcn_mfma_f32_16x16x32_bf16((a), (b), (c), 0, 0, 0)

__device__ __forceinline__ us f2bf(float f) {
  union { float f; unsigned u; } v; v.f = f;
  unsigned r = v.u + 0x7fffu + ((v.u >> 16) & 1u);   // RNE
  return (us)(r >> 16);
}
__device__ __forceinline__ float bf2f(us u) {
  union { unsigned u; float f; } v; v.u = ((unsigned)u) << 16;
  return v.f;
}
// async global->LDS, 16B per lane; LDS dst = wave-uniform base + lane*16
__device__ __forceinline__ void async16(const us* g, us* l) {
  __builtin_amdgcn_global_load_lds(
      (const __attribute__((address_space(1))) unsigned int*)(g),
      (__attribute__((address_space(3))) unsigned int*)(l), 16, 0, 0);
}

// ---------------------------------------------------------------------------
// Cast x + 4 weights fp32 -> bf16.
// ---------------------------------------------------------------------------
__global__ __launch_bounds__(256) void cast_all(
    const float* __restrict__ x,  const float* __restrict__ mq,
    const float* __restrict__ mk, const float* __restrict__ mv,
    const float* __restrict__ wo,
    us* __restrict__ xb, us* __restrict__ wqb, us* __restrict__ wkb,
    us* __restrict__ wvb, us* __restrict__ wob)
{
  size_t i = ((size_t)blockIdx.x * 256 + threadIdx.x) * 8;
  const float* src; us* dst; size_t j;
  if      (i <  8388608) { src = x;  dst = xb;  j = i; }
  else if (i <  8912896) { src = mq; dst = wqb; j = i -  8388608; }
  else if (i <  9437184) { src = mk; dst = wkb; j = i -  8912896; }
  else if (i < 10485760) { src = mv; dst = wvb; j = i -  9437184; }
  else if (i < 11534336) { src = wo; dst = wob; j = i - 10485760; }
  else return;
  float4 a = *(const float4*)(src + j);
  float4 b = *(const float4*)(src + j + 4);
  short8 o;
  o[0] = (short)f2bf(a.x); o[1] = (short)f2bf(a.y);
  o[2] = (short)f2bf(a.z); o[3] = (short)f2bf(a.w);
  o[4] = (short)f2bf(b.x); o[5] = (short)f2bf(b.y);
  o[6] = (short)f2bf(b.z); o[7] = (short)f2bf(b.w);
  *(short8*)(dst + j) = o;
}

// ---------------------------------------------------------------------------
// bf16 MFMA GEMM: out[M,N] = A[M,K] @ W[N,K]^T + bias. 128x128 tile, BK=64,
// global_load_lds staging with 8-chunk XOR swizzle (rows 128B).
// ---------------------------------------------------------------------------
template<int OUT_BF16>
__global__ __launch_bounds__(256) void gemm_mfma(
    const us* __restrict__ A, const us* __restrict__ W,
    const float* __restrict__ bias, void* __restrict__ outp,
    int M, int N, int K)
{
  __shared__ __align__(16) us As[128 * 64];
  __shared__ __align__(16) us Ws[128 * 64];
  const int t = threadIdx.x, lane = t & 63, wid = t >> 6;
  const int wr = wid >> 1, wc = wid & 1;
  const int quad = lane >> 4, l15 = lane & 15, l7 = l15 & 7;
  const int m0 = blockIdx.y * 128, n0 = blockIdx.x * 128;

  floatx4 acc[4][4];
#pragma unroll
  for (int i = 0; i < 4; i++)
#pragma unroll
    for (int j = 0; j < 4; j++) acc[i][j] = (floatx4){0.f, 0.f, 0.f, 0.f};

  for (int k0 = 0; k0 < K; k0 += 64) {
    __syncthreads();
#pragma unroll
    for (int j = 0; j < 4; j++) {
      int f = (wid * 4 + j) * 64 + lane;
      int row = f >> 3, sc = (f & 7) ^ (row & 7);
      async16(A + (size_t)(m0 + row) * K + k0 + sc * 8, &As[f * 8]);
      async16(W + (size_t)(n0 + row) * K + k0 + sc * 8, &Ws[f * 8]);
    }
    __syncthreads();
    short8 aF[4][2], bF[4][2];
#pragma unroll
    for (int fm = 0; fm < 4; fm++) {
      int ra = wr * 64 + fm * 16 + l15;
      int rb = wc * 64 + fm * 16 + l15;
#pragma unroll
      for (int c = 0; c < 2; c++) {
        aF[fm][c] = *(const short8*)&As[ra * 64 + (((c << 2) + quad) ^ l7) * 8];
        bF[fm][c] = *(const short8*)&Ws[rb * 64 + (((c << 2) + quad) ^ l7) * 8];
      }
    }
#pragma unroll
    for (int i = 0; i < 4; i++)
#pragma unroll
      for (int j = 0; j < 4; j++) {
        floatx4 d = MFMA_BF16(aF[i][0], bF[j][0], acc[i][j]);
        acc[i][j] = MFMA_BF16(aF[i][1], bF[j][1], d);
      }
  }

#pragma unroll
  for (int fn = 0; fn < 4; fn++) {
    int col = n0 + wc * 64 + fn * 16 + l15;
    float bv = bias[col];
#pragma unroll
    for (int fm = 0; fm < 4; fm++) {
#pragma unroll
      for (int r = 0; r < 4; r++) {
        int m = m0 + wr * 64 + fm * 16 + quad * 4 + r;
        float v = acc[fm][fn][r] + bv;
        if (OUT_BF16)
          ((us*)outp)[(size_t)m * N + col] = f2bf(v);
        else
          ((float*)outp)[(size_t)m * N + col] = v;
      }
    }
  }
}

// ---------------------------------------------------------------------------
// Pass 1: invZ[bh,k] = 1 / sum_q exp((q.k + mask[b,q])/8)  (softmax over q).
// Block = 128 keys x bh; wave owns 32 keys (K A-frags in regs). Q streamed in
// 128-row LDS tiles, double-buffered via global_load_lds + XOR swizzle.
// S^T = K*Q^T: D col=q(l15), row=key(quad*4+r).
// ---------------------------------------------------------------------------
__global__ __launch_bounds__(256, 2) void attn_pass1(
    const us* __restrict__ Q_, const us* __restrict__ K_,
    const float* __restrict__ mask, float* __restrict__ invZ)
{
  __shared__ __align__(16) us Qs[2][128 * 64];
  const int t = threadIdx.x, lane = t & 63, wid = t >> 6;
  const int quad = lane >> 4, l15 = lane & 15, l7 = l15 & 7;
  const int bh = blockIdx.y, b = bh >> 3;
  const int kt = blockIdx.x * 128;
  const us* Kb = K_ + (size_t)bh * Cc * 64;
  const us* Qb = Q_ + (size_t)bh * Cc * 64;
  const float* mrow = mask + (size_t)b * Cc;

  short8 kA[2][2];
#pragma unroll
  for (int kf = 0; kf < 2; kf++)
#pragma unroll
    for (int c = 0; c < 2; c++)
      kA[kf][c] = *(const short8*)(Kb + (size_t)(kt + wid * 32 + kf * 16 + l15) * 64 + c * 32 + quad * 8);

  float zacc[2][4] = {};

#pragma unroll
  for (int j = 0; j < 4; j++) {   // stage tile 0
    int f = (wid * 4 + j) * 64 + lane;
    int row = f >> 3, sc = (f & 7) ^ (row & 7);
    async16(Qb + (size_t)row * 64 + sc * 8, &Qs[0][f * 8]);
  }
  __syncthreads();

  int p = 0;
  for (int it = 0; it < 16; it++) {
    if (it + 1 < 16) {
#pragma unroll
      for (int j = 0; j < 4; j++) {
        int f = (wid * 4 + j) * 64 + lane;
        int row = f >> 3, sc = (f & 7) ^ (row & 7);
        async16(Qb + (size_t)((it + 1) * 128 + row) * 64 + sc * 8, &Qs[1 - p][f * 8]);
      }
    }
    const us* Qsp = Qs[p];
#pragma unroll
    for (int qf = 0; qf < 8; qf++) {
      int row = qf * 16 + l15;
      short8 q0 = *(const short8*)&Qsp[row * 64 + ((quad) ^ l7) * 8];
      short8 q1 = *(const short8*)&Qsp[row * 64 + ((4 + quad) ^ l7) * 8];
      float mv = mrow[it * 128 + qf * 16 + l15] * 0.125f;
#pragma unroll
      for (int kf = 0; kf < 2; kf++) {
        floatx4 d = (floatx4){0.f, 0.f, 0.f, 0.f};
        d = MFMA_BF16(kA[kf][0], q0, d);
        d = MFMA_BF16(kA[kf][1], q1, d);
#pragma unroll
        for (int r = 0; r < 4; r++)
          zacc[kf][r] += __expf(fmaf(d[r], 0.125f, mv));
      }
    }
    __syncthreads();
    p ^= 1;
  }

#pragma unroll
  for (int kf = 0; kf < 2; kf++)
#pragma unroll
    for (int r = 0; r < 4; r++) {
      float v = zacc[kf][r];
      v += __shfl_xor(v, 1); v += __shfl_xor(v, 2);
      v += __shfl_xor(v, 4); v += __shfl_xor(v, 8);
      if (l15 == 0)
        invZ[(size_t)bh * Cc + kt + wid * 32 + kf * 16 + quad * 4 + r] = 1.0f / v;
    }
}

// ---------------------------------------------------------------------------
// Transpose + scale: VT[bh][dv][c] = V[bh][c][dv] * invZ[bh][c]  (bf16).
// ---------------------------------------------------------------------------
__global__ __launch_bounds__(256) void transpose_v(
    const us* __restrict__ V, const float* __restrict__ invZ,
    us* __restrict__ VT)
{
  __shared__ __align__(16) us Vs[32][136];
  __shared__ float izs[32];
  const int bh = blockIdx.y, ct = blockIdx.x * 32;
  const int t = threadIdx.x;
  const us* Vb  = V  + (size_t)bh * Cc * 128;
  us*       VTb = VT + (size_t)bh * 128 * Cc;
#pragma unroll
  for (int i = 0; i < 2; i++) {
    int idx = t + i * 256, c = idx >> 4, d0 = (idx & 15) * 8;
    *(short8*)&Vs[c][d0] = *(const short8*)(Vb + (size_t)(ct + c) * 128 + d0);
  }
  if (t < 32) izs[t] = invZ[(size_t)bh * Cc + ct + t];
  __syncthreads();
#pragma unroll
  for (int i = 0; i < 2; i++) {
    int idx = t + i * 256, dv = idx >> 2, cb = (idx & 3) * 8;
    short8 o;
#pragma unroll
    for (int j = 0; j < 8; j++)
      o[j] = (short)f2bf(bf2f(Vs[cb + j][dv]) * izs[cb + j]);
    *(short8*)(VTb + (size_t)dv * Cc + ct + cb) = o;
  }
}

// ---------------------------------------------------------------------------
// Pass 2: A[q,:] = sum_k exp((q.k+mask[q])/8) * Vscaled[k,:].
// Block = 128 q x bh. K-tile 64x64 + VT-tile 128x64 double-buffered in LDS
// (global_load_lds, XOR swizzle). S^T via MFMA(A=K,B=Q) -> exp -> packed
// 8B writes into swizzled Ps[q][key] -> A-operand b128 reads for PV MFMA.
// One barrier per K-iteration; LDS total = 64 KB -> 2 blocks/CU.
// ---------------------------------------------------------------------------
__global__ __launch_bounds__(256, 2) void attn_pass2(
    const us* __restrict__ Q_, const us* __restrict__ K_,
    const us* __restrict__ VT_, const float* __restrict__ mask,
    us* __restrict__ Ab)
{
  __shared__ __align__(16) us Ks[2][64 * 64];     // 16 KB
  __shared__ __align__(16) us VTs[2][128 * 64];   // 32 KB
  __shared__ __align__(16) us Ps[128 * 64];       // 16 KB
  const int t = threadIdx.x, lane = t & 63, wid = t >> 6;
  const int quad = lane >> 4, l15 = lane & 15, l7 = l15 & 7;
  const int bh = blockIdx.y, b = bh >> 3;
  const int qt = blockIdx.x * 128;
  const us* Qb  = Q_  + (size_t)bh * Cc * 64;
  const us* Kb  = K_  + (size_t)bh * Cc * 64;
  const us* VTb = VT_ + (size_t)bh * 128 * Cc;

  // Q B-frags + scaled mask, resident for the whole block
  short8 qB[2][2];
  float mvs[2];
#pragma unroll
  for (int qf = 0; qf < 2; qf++) {
    int q = qt + wid * 32 + qf * 16 + l15;
#pragma unroll
    for (int c = 0; c < 2; c++)
      qB[qf][c] = *(const short8*)(Qb + (size_t)q * 64 + c * 32 + quad * 8);
    mvs[qf] = mask[(size_t)b * Cc + q] * 0.125f;
  }

  floatx4 acc[2][8];
#pragma unroll
  for (int qf = 0; qf < 2; qf++)
#pragma unroll
    for (int fn = 0; fn < 8; fn++) acc[qf][fn] = (floatx4){0.f, 0.f, 0.f, 0.f};

  // stage tile kb=0 into buffer 0
#pragma unroll
  for (int j = 0; j < 2; j++) {
    int f = (wid * 2 + j) * 64 + lane;
    int row = f >> 3, sc = (f & 7) ^ (row & 7);
    async16(Kb + (size_t)row * 64 + sc * 8, &Ks[0][f * 8]);
  }
#pragma unroll
  for (int j = 0; j < 4; j++) {
    int f = (wid * 4 + j) * 64 + lane;
    int row = f >> 3, sc = (f & 7) ^ (row & 7);
    async16(VTb + (size_t)row * Cc + sc * 8, &VTs[0][f * 8]);
  }
  __syncthreads();

  int p = 0;
  for (int kb = 0; kb < Cc; kb += 64) {
    if (kb + 64 < Cc) {    // prefetch next tile into 1-p (overlaps compute)
#pragma unroll
      for (int j = 0; j < 2; j++) {
        int f = (wid * 2 + j) * 64 + lane;
        int row = f >> 3, sc = (f & 7) ^ (row & 7);
        async16(Kb + (size_t)(kb + 64 + row) * 64 + sc * 8, &Ks[1 - p][f * 8]);
      }
#pragma unroll
      for (int j = 0; j < 4; j++) {
        int f = (wid * 4 + j) * 64 + lane;
        int row = f >> 3, sc = (f & 7) ^ (row & 7);
        async16(VTb + (size_t)row * Cc + kb + 64 + sc * 8, &VTs[1 - p][f * 8]);
      }
    }
    const us* Ksp = Ks[p];
    const us* Vsp = VTs[p];

    // S^T stage: 16 keys x 16 q per frag-pair
    short8 kA[4][2];
#pragma unroll
    for (int kf = 0; kf < 4; kf++) {
      int row = kf * 16 + l15;
#pragma unroll
      for (int c = 0; c < 2; c++)
        kA[kf][c] = *(const short8*)&Ksp[row * 64 + (((c << 2) + quad) ^ l7) * 8];
    }
#pragma unroll
    for (int kf = 0; kf < 4; kf++) {
#pragma unroll
      for (int qf = 0; qf < 2; qf++) {
        floatx4 d = (floatx4){0.f, 0.f, 0.f, 0.f};
        d = MFMA_BF16(kA[kf][0], qB[qf][0], d);
        d = MFMA_BF16(kA[kf][1], qB[qf][1], d);
        ushortx4 pk;
#pragma unroll
        for (int r = 0; r < 4; r++)
          pk[r] = f2bf(__expf(fmaf(d[r], 0.125f, mvs[qf])));
        int prow = wid * 32 + qf * 16 + l15;
        *(ushortx4*)&Ps[prow * 64 + (((kf << 1) + (quad >> 1)) ^ l7) * 8 + (quad & 1) * 4] = pk;
      }
    }

    // PV stage (Ps is wave-private; same-wave lgkmcnt ordering suffices)
    short8 pA[2][2];
#pragma unroll
    for (int qf = 0; qf < 2; qf++) {
      int prow = wid * 32 + qf * 16 + l15;
#pragma unroll
      for (int kc = 0; kc < 2; kc++)
        pA[qf][kc] = *(const short8*)&Ps[prow * 64 + (((kc << 2) + quad) ^ l7) * 8];
    }
#pragma unroll
    for (int fn = 0; fn < 8; fn++) {
      int vrow = fn * 16 + l15;
#pragma unroll
      for (int kc = 0; kc < 2; kc++) {
        short8 vB = *(const short8*)&Vsp[vrow * 64 + (((kc << 2) + quad) ^ l7) * 8];
#pragma unroll
        for (int qf = 0; qf < 2; qf++)
          acc[qf][fn] = MFMA_BF16(pA[qf][kc], vB, acc[qf][fn]);
      }
    }
    __syncthreads();   // drains prefetch (vmcnt) + frees buffers for next iter
    p ^= 1;
  }

#pragma unroll
  for (int qf = 0; qf < 2; qf++)
#pragma unroll
    for (int fn = 0; fn < 8; fn++)
#pragma unroll
      for (int r = 0; r < 4; r++) {
        int q = qt + wid * 32 + qf * 16 + quad * 4 + r;
        Ab[((size_t)bh * Cc + q) * 128 + fn * 16 + l15] = f2bf(acc[qf][fn][r]);
      }
}

// ---------------------------------------------------------------------------
extern "C" void kernel_launch(void* const* d_in, const int* in_sizes, int n_in,
                              void* d_out, int out_size, void* d_ws, size_t ws_size,
                              hipStream_t stream)
{
  const float* x    = (const float*)d_in[0];
  const float* mask = (const float*)d_in[1];
  const float* Mq_w = (const float*)d_in[2];
  const float* Mq_b = (const float*)d_in[3];
  const float* Mk_w = (const float*)d_in[4];
  const float* Mk_b = (const float*)d_in[5];
  const float* Mv_w = (const float*)d_in[6];
  const float* Mv_b = (const float*)d_in[7];
  const float* Wo_w = (const float*)d_in[8];
  const float* Wo_b = (const float*)d_in[9];
  float* outp = (float*)d_out;

  us* xb  = (us*)d_ws;
  us* wq  = xb  + 8388608;     // x:    8192x1024
  us* wk  = wq  + 524288;      // Mq_w: 512x1024
  us* wv  = wk  + 524288;
  us* wo  = wv  + 1048576;     // Mv_w: 1024x1024
  us* Qb  = wo  + 1048576;     // Wo_w: 1024x1024
  us* Kb  = Qb  + 4194304;     // Q:    8192x512
  us* Vb  = Kb  + 4194304;
  us* VTb = Vb  + 8388608;     // V:    8192x1024
  us* Ab  = VTb + 8388608;     // VT:   32x128x2048
  float* invZ = (float*)(Ab + 8388608);   // 32x2048 fp32

  dim3 blk(256);
  cast_all<<<5632, blk, 0, stream>>>(x, Mq_w, Mk_w, Mv_w, Wo_w, xb, wq, wk, wv, wo);

  gemm_mfma<1><<<dim3(4, 64), blk, 0, stream>>>(xb, wq, Mq_b, Qb, Mrows, 512, 1024);
  gemm_mfma<1><<<dim3(4, 64), blk, 0, stream>>>(xb, wk, Mk_b, Kb, Mrows, 512, 1024);
  gemm_mfma<1><<<dim3(8, 64), blk, 0, stream>>>(xb, wv, Mv_b, Vb, Mrows, 1024, 1024);

  attn_pass1<<<dim3(16, 32), blk, 0, stream>>>(Qb, Kb, mask, invZ);
  transpose_v<<<dim3(64, 32), blk, 0, stream>>>(Vb, invZ, VTb);
  attn_pass2<<<dim3(16, 32), blk, 0, stream>>>(Qb, Kb, VTb, mask, Ab);

  gemm_mfma<0><<<dim3(8, 64), blk, 0, stream>>>(Ab, wo, Wo_b, outp, Mrows, 1024, 1024);
}

// Round 5
// 289.667 us; speedup vs baseline: 6.9634x; 1.0948x over previous
//
#include <hip/hip_runtime.h>
#include <hip/hip_bf16.h>
#include <cstdint>
#include <cstddef>

constexpr int Cc = 2048;         // sequence length
constexpr int Mrows = 8192;      // B*C
constexpr float SC2 = 0.18033688011112042f;   // 0.125 * log2(e)

typedef __attribute__((ext_vector_type(8))) short short8;
typedef __attribute__((ext_vector_type(4))) float floatx4;
typedef unsigned short us;

#define MFMA_BF16(a, b, c) __builtin_amdgcn_mfma_f32_16x16x32_bf16((a), (b), (c), 0, 0, 0)
#define EXP2F(x) __builtin_amdgcn_exp2f(x)

__device__ __forceinline__ us f2bf(float f) {
  union { float f; unsigned u; } v; v.f = f;
  unsigned r = v.u + 0x7fffu + ((v.u >> 16) & 1u);   // RNE
  return (us)(r >> 16);
}
__device__ __forceinline__ float bf2f(us u) {
  union { unsigned u; float f; } v; v.u = ((unsigned)u) << 16;
  return v.f;
}
__device__ __forceinline__ uint2 pack4bf(float e0, float e1, float e2, float e3) {
  union { __hip_bfloat162 h; unsigned u; } a, b;
  a.h = __float22bfloat162_rn(float2{e0, e1});
  b.h = __float22bfloat162_rn(float2{e2, e3});
  return uint2{a.u, b.u};
}
// async global->LDS, 16B/lane; LDS dst = wave-uniform base + lane*16
__device__ __forceinline__ void async16(const us* g, us* l) {
  __builtin_amdgcn_global_load_lds(
      (const __attribute__((address_space(1))) unsigned int*)(g),
      (__attribute__((address_space(3))) unsigned int*)(l), 16, 0, 0);
}

// ---------------------------------------------------------------------------
// Cast x + 4 weights fp32 -> bf16 (wq|wk|wv land contiguously = fused W).
// ---------------------------------------------------------------------------
__global__ __launch_bounds__(256) void cast_all(
    const float* __restrict__ x,  const float* __restrict__ mq,
    const float* __restrict__ mk, const float* __restrict__ mv,
    const float* __restrict__ wo,
    us* __restrict__ xb, us* __restrict__ wqb, us* __restrict__ wkb,
    us* __restrict__ wvb, us* __restrict__ wob)
{
  size_t i = ((size_t)blockIdx.x * 256 + threadIdx.x) * 8;
  const float* src; us* dst; size_t j;
  if      (i <  8388608) { src = x;  dst = xb;  j = i; }
  else if (i <  8912896) { src = mq; dst = wqb; j = i -  8388608; }
  else if (i <  9437184) { src = mk; dst = wkb; j = i -  8912896; }
  else if (i < 10485760) { src = mv; dst = wvb; j = i -  9437184; }
  else if (i < 11534336) { src = wo; dst = wob; j = i - 10485760; }
  else return;
  float4 a = *(const float4*)(src + j);
  float4 b = *(const float4*)(src + j + 4);
  short8 o;
  o[0] = (short)f2bf(a.x); o[1] = (short)f2bf(a.y);
  o[2] = (short)f2bf(a.z); o[3] = (short)f2bf(a.w);
  o[4] = (short)f2bf(b.x); o[5] = (short)f2bf(b.y);
  o[6] = (short)f2bf(b.z); o[7] = (short)f2bf(b.w);
  *(short8*)(dst + j) = o;
}

// ---------------------------------------------------------------------------
// Fused QKV GEMM: [Q|K|V](8192x2048) = x(8192x1024) @ Wall(2048x1024)^T + b.
// 128x128 tile, BK=64, async staging + XOR swizzle. Flat grid 1024,
// XCD swizzle: n-tile = (id&7)*2 + bit -> each XCD reuses 2 W col-blocks.
// ---------------------------------------------------------------------------
__global__ __launch_bounds__(256, 3) void gemm_qkv(
    const us* __restrict__ A, const us* __restrict__ Wall,
    const float* __restrict__ bq, const float* __restrict__ bk,
    const float* __restrict__ bv,
    us* __restrict__ Qo, us* __restrict__ Ko, us* __restrict__ Vo)
{
  __shared__ __align__(16) us As[128 * 64];
  __shared__ __align__(16) us Ws[128 * 64];
  const int t = threadIdx.x, lane = t & 63, wid = t >> 6;
  const int wr = wid >> 1, wc = wid & 1;
  const int quad = lane >> 4, l15 = lane & 15, l7 = l15 & 7;
  const int id = blockIdx.x;
  const int nt = (id & 7) * 2 + ((id >> 3) & 1);
  const int mt = id >> 4;
  const int m0 = mt * 128, n0 = nt * 128;
  const int K = 1024;

  floatx4 acc[4][4];
#pragma unroll
  for (int i = 0; i < 4; i++)
#pragma unroll
    for (int j = 0; j < 4; j++) acc[i][j] = (floatx4){0.f, 0.f, 0.f, 0.f};

  for (int k0 = 0; k0 < K; k0 += 64) {
    __syncthreads();
#pragma unroll
    for (int j = 0; j < 4; j++) {
      int f = (wid * 4 + j) * 64 + lane;
      int row = f >> 3, sc = (f & 7) ^ (row & 7);
      async16(A    + (size_t)(m0 + row) * K + k0 + sc * 8, &As[f * 8]);
      async16(Wall + (size_t)(n0 + row) * K + k0 + sc * 8, &Ws[f * 8]);
    }
    __syncthreads();
    short8 aF[4][2], bF[4][2];
#pragma unroll
    for (int fm = 0; fm < 4; fm++) {
      int ra = wr * 64 + fm * 16 + l15;
      int rb = wc * 64 + fm * 16 + l15;
#pragma unroll
      for (int c = 0; c < 2; c++) {
        aF[fm][c] = *(const short8*)&As[ra * 64 + (((c << 2) + quad) ^ l7) * 8];
        bF[fm][c] = *(const short8*)&Ws[rb * 64 + (((c << 2) + quad) ^ l7) * 8];
      }
    }
#pragma unroll
    for (int i = 0; i < 4; i++)
#pragma unroll
      for (int j = 0; j < 4; j++) {
        floatx4 d = MFMA_BF16(aF[i][0], bF[j][0], acc[i][j]);
        acc[i][j] = MFMA_BF16(aF[i][1], bF[j][1], d);
      }
  }

  us* dst; const float* bias; int Nout, c0;
  if (nt < 4)      { dst = Qo; bias = bq; Nout = 512;  c0 = n0; }
  else if (nt < 8) { dst = Ko; bias = bk; Nout = 512;  c0 = n0 - 512; }
  else             { dst = Vo; bias = bv; Nout = 1024; c0 = n0 - 1024; }

#pragma unroll
  for (int fn = 0; fn < 4; fn++) {
    int col = c0 + wc * 64 + fn * 16 + l15;
    float bvv = bias[col];
#pragma unroll
    for (int fm = 0; fm < 4; fm++)
#pragma unroll
      for (int r = 0; r < 4; r++) {
        int m = m0 + wr * 64 + fm * 16 + quad * 4 + r;
        dst[(size_t)m * Nout + col] = f2bf(acc[fm][fn][r] + bvv);
      }
  }
}

// ---------------------------------------------------------------------------
// Output GEMM: out(8192x1024 fp32) = Ab @ Wo^T + b. Flat grid 512,
// XCD swizzle: n-tile = id&7.
// ---------------------------------------------------------------------------
__global__ __launch_bounds__(256, 3) void gemm_out(
    const us* __restrict__ A, const us* __restrict__ W,
    const float* __restrict__ bias, float* __restrict__ outp)
{
  __shared__ __align__(16) us As[128 * 64];
  __shared__ __align__(16) us Ws[128 * 64];
  const int t = threadIdx.x, lane = t & 63, wid = t >> 6;
  const int wr = wid >> 1, wc = wid & 1;
  const int quad = lane >> 4, l15 = lane & 15, l7 = l15 & 7;
  const int id = blockIdx.x;
  const int m0 = (id >> 3) * 128, n0 = (id & 7) * 128;
  const int K = 1024, N = 1024;

  floatx4 acc[4][4];
#pragma unroll
  for (int i = 0; i < 4; i++)
#pragma unroll
    for (int j = 0; j < 4; j++) acc[i][j] = (floatx4){0.f, 0.f, 0.f, 0.f};

  for (int k0 = 0; k0 < K; k0 += 64) {
    __syncthreads();
#pragma unroll
    for (int j = 0; j < 4; j++) {
      int f = (wid * 4 + j) * 64 + lane;
      int row = f >> 3, sc = (f & 7) ^ (row & 7);
      async16(A + (size_t)(m0 + row) * K + k0 + sc * 8, &As[f * 8]);
      async16(W + (size_t)(n0 + row) * K + k0 + sc * 8, &Ws[f * 8]);
    }
    __syncthreads();
    short8 aF[4][2], bF[4][2];
#pragma unroll
    for (int fm = 0; fm < 4; fm++) {
      int ra = wr * 64 + fm * 16 + l15;
      int rb = wc * 64 + fm * 16 + l15;
#pragma unroll
      for (int c = 0; c < 2; c++) {
        aF[fm][c] = *(const short8*)&As[ra * 64 + (((c << 2) + quad) ^ l7) * 8];
        bF[fm][c] = *(const short8*)&Ws[rb * 64 + (((c << 2) + quad) ^ l7) * 8];
      }
    }
#pragma unroll
    for (int i = 0; i < 4; i++)
#pragma unroll
      for (int j = 0; j < 4; j++) {
        floatx4 d = MFMA_BF16(aF[i][0], bF[j][0], acc[i][j]);
        acc[i][j] = MFMA_BF16(aF[i][1], bF[j][1], d);
      }
  }

#pragma unroll
  for (int fn = 0; fn < 4; fn++) {
    int col = n0 + wc * 64 + fn * 16 + l15;
    float bvv = bias[col];
#pragma unroll
    for (int fm = 0; fm < 4; fm++)
#pragma unroll
      for (int r = 0; r < 4; r++) {
        int m = m0 + wr * 64 + fm * 16 + quad * 4 + r;
        outp[(size_t)m * N + col] = acc[fm][fn][r] + bvv;
      }
  }
}

// ---------------------------------------------------------------------------
// Pass 1: invZ[bh,k] = 1 / sum_q exp((q.k + mask[b,q])/8)  (softmax over q).
// Flat grid 512, XCD swizzle keeps each bh's Q stream on one XCD's L2.
// ---------------------------------------------------------------------------
__global__ __launch_bounds__(256, 2) void attn_pass1(
    const us* __restrict__ Q_, const us* __restrict__ K_,
    const float* __restrict__ mask, float* __restrict__ invZ)
{
  __shared__ __align__(16) us Qs[2][128 * 64];
  const int t = threadIdx.x, lane = t & 63, wid = t >> 6;
  const int quad = lane >> 4, l15 = lane & 15, l7 = l15 & 7;
  const int id = blockIdx.x;
  const int bh = (id & 7) * 4 + ((id >> 3) & 3);
  const int kt = (id >> 5) * 128;
  const int b = bh >> 3;
  const us* Kb = K_ + (size_t)bh * Cc * 64;
  const us* Qb = Q_ + (size_t)bh * Cc * 64;
  const float* mrow = mask + (size_t)b * Cc;

  short8 kA[2][2];
#pragma unroll
  for (int kf = 0; kf < 2; kf++)
#pragma unroll
    for (int c = 0; c < 2; c++)
      kA[kf][c] = *(const short8*)(Kb + (size_t)(kt + wid * 32 + kf * 16 + l15) * 64 + c * 32 + quad * 8);

  float zacc[2][4] = {};

#pragma unroll
  for (int j = 0; j < 4; j++) {   // stage tile 0
    int f = (wid * 4 + j) * 64 + lane;
    int row = f >> 3, sc = (f & 7) ^ (row & 7);
    async16(Qb + (size_t)row * 64 + sc * 8, &Qs[0][f * 8]);
  }
  __syncthreads();

  int p = 0;
  for (int it = 0; it < 16; it++) {
    if (it + 1 < 16) {
#pragma unroll
      for (int j = 0; j < 4; j++) {
        int f = (wid * 4 + j) * 64 + lane;
        int row = f >> 3, sc = (f & 7) ^ (row & 7);
        async16(Qb + (size_t)((it + 1) * 128 + row) * 64 + sc * 8, &Qs[1 - p][f * 8]);
      }
    }
    const us* Qsp = Qs[p];
#pragma unroll
    for (int qf = 0; qf < 8; qf++) {
      int row = qf * 16 + l15;
      short8 q0 = *(const short8*)&Qsp[row * 64 + ((quad) ^ l7) * 8];
      short8 q1 = *(const short8*)&Qsp[row * 64 + ((4 + quad) ^ l7) * 8];
      float mv = mrow[it * 128 + qf * 16 + l15] * SC2;
#pragma unroll
      for (int kf = 0; kf < 2; kf++) {
        floatx4 d = (floatx4){0.f, 0.f, 0.f, 0.f};
        d = MFMA_BF16(kA[kf][0], q0, d);
        d = MFMA_BF16(kA[kf][1], q1, d);
#pragma unroll
        for (int r = 0; r < 4; r++)
          zacc[kf][r] += EXP2F(fmaf(d[r], SC2, mv));
      }
    }
    __syncthreads();
    p ^= 1;
  }

#pragma unroll
  for (int kf = 0; kf < 2; kf++)
#pragma unroll
    for (int r = 0; r < 4; r++) {
      float v = zacc[kf][r];
      v += __shfl_xor(v, 1); v += __shfl_xor(v, 2);
      v += __shfl_xor(v, 4); v += __shfl_xor(v, 8);
      if (l15 == 0)
        invZ[(size_t)bh * Cc + kt + wid * 32 + kf * 16 + quad * 4 + r] = 1.0f / v;
    }
}

// ---------------------------------------------------------------------------
// Transpose + scale: VT[bh][dv][c] = V[bh][c][dv] * invZ[bh][c]  (bf16).
// ---------------------------------------------------------------------------
__global__ __launch_bounds__(256) void transpose_v(
    const us* __restrict__ V, const float* __restrict__ invZ,
    us* __restrict__ VT)
{
  __shared__ __align__(16) us Vs[32][136];
  __shared__ float izs[32];
  const int bh = blockIdx.y, ct = blockIdx.x * 32;
  const int t = threadIdx.x;
  const us* Vb  = V  + (size_t)bh * Cc * 128;
  us*       VTb = VT + (size_t)bh * 128 * Cc;
#pragma unroll
  for (int i = 0; i < 2; i++) {
    int idx = t + i * 256, c = idx >> 4, d0 = (idx & 15) * 8;
    *(short8*)&Vs[c][d0] = *(const short8*)(Vb + (size_t)(ct + c) * 128 + d0);
  }
  if (t < 32) izs[t] = invZ[(size_t)bh * Cc + ct + t];
  __syncthreads();
#pragma unroll
  for (int i = 0; i < 2; i++) {
    int idx = t + i * 256, dv = idx >> 2, cb = (idx & 3) * 8;
    short8 o;
#pragma unroll
    for (int j = 0; j < 8; j++)
      o[j] = (short)f2bf(bf2f(Vs[cb + j][dv]) * izs[cb + j]);
    *(short8*)(VTb + (size_t)dv * Cc + ct + cb) = o;
  }
}

// ---------------------------------------------------------------------------
// Pass 2: A[q,:] = sum_k exp((q.k+mask[q])/8) * Vscaled[k,:].
// Flat grid 512, XCD swizzle. K-frags in registers (global, prefetched);
// VT tile + Ps both double-buffered in LDS. Software-pipelined: iter kb does
// S^T(kb+64)->Ps[1-s] while PV(kb) reads Ps[s]/VTs[p]. One barrier/iter.
// S^T split 2x2 over (key-half,q-half); PV split 2x2 over (q-half,dv-half).
// ---------------------------------------------------------------------------
__global__ __launch_bounds__(256, 2) void attn_pass2(
    const us* __restrict__ Q_, const us* __restrict__ K_,
    const us* __restrict__ VT_, const float* __restrict__ mask,
    us* __restrict__ Ab)
{
  __shared__ __align__(16) us VTs[2][128 * 64];   // 32 KB
  __shared__ __align__(16) us Ps[2][128 * 64];    // 32 KB
  const int t = threadIdx.x, lane = t & 63, wid = t >> 6;
  const int quad = lane >> 4, l15 = lane & 15, l7 = l15 & 7;
  const int id = blockIdx.x;
  const int bh = (id & 7) * 4 + ((id >> 3) & 3);
  const int qt = (id >> 5) * 128;
  const int b = bh >> 3;
  const us* Qb  = Q_  + (size_t)bh * Cc * 64;
  const us* Kb  = K_  + (size_t)bh * Cc * 64;
  const us* VTb = VT_ + (size_t)bh * 128 * Cc;

  const int kHalf = wid & 1, qHalfS = wid >> 1;   // S^T split
  const int qPV = wid & 1, dvPV = wid >> 1;       // PV split

  // Q B-frags + prescaled mask for this wave's S^T q-range
  short8 qB[4][2];
  float mv2[4];
#pragma unroll
  for (int qq = 0; qq < 4; qq++) {
    int q = qt + qHalfS * 64 + qq * 16 + l15;
#pragma unroll
    for (int c = 0; c < 2; c++)
      qB[qq][c] = *(const short8*)(Qb + (size_t)q * 64 + c * 32 + quad * 8);
    mv2[qq] = mask[(size_t)b * Cc + q] * SC2;
  }

  floatx4 acc[4][4];
#pragma unroll
  for (int i = 0; i < 4; i++)
#pragma unroll
    for (int j = 0; j < 4; j++) acc[i][j] = (floatx4){0.f, 0.f, 0.f, 0.f};

  // K frags (registers, from global): keys for tile kb=0
  short8 kA[2][2];
#pragma unroll
  for (int kk = 0; kk < 2; kk++)
#pragma unroll
    for (int c = 0; c < 2; c++)
      kA[kk][c] = *(const short8*)(Kb + (size_t)((kHalf * 2 + kk) * 16 + l15) * 64 + c * 32 + quad * 8);

  // stage VT tile 0
#pragma unroll
  for (int j = 0; j < 4; j++) {
    int f = (wid * 4 + j) * 64 + lane;
    int row = f >> 3, sc = (f & 7) ^ (row & 7);
    async16(VTb + (size_t)row * Cc + sc * 8, &VTs[0][f * 8]);
  }

  // prologue: S^T(0) -> Ps[0]
#pragma unroll
  for (int kk = 0; kk < 2; kk++) {
    int kf = kHalf * 2 + kk;
#pragma unroll
    for (int qq = 0; qq < 4; qq++) {
      floatx4 d = (floatx4){0.f, 0.f, 0.f, 0.f};
      d = MFMA_BF16(kA[kk][0], qB[qq][0], d);
      d = MFMA_BF16(kA[kk][1], qB[qq][1], d);
      uint2 pk = pack4bf(EXP2F(fmaf(d[0], SC2, mv2[qq])),
                         EXP2F(fmaf(d[1], SC2, mv2[qq])),
                         EXP2F(fmaf(d[2], SC2, mv2[qq])),
                         EXP2F(fmaf(d[3], SC2, mv2[qq])));
      int prow = qHalfS * 64 + qq * 16 + l15;
      *(uint2*)&Ps[0][prow * 64 + (((kf << 1) + (quad >> 1)) ^ l7) * 8 + (quad & 1) * 4] = pk;
    }
  }
  // preload K frags for kb=64
#pragma unroll
  for (int kk = 0; kk < 2; kk++)
#pragma unroll
    for (int c = 0; c < 2; c++)
      kA[kk][c] = *(const short8*)(Kb + (size_t)(64 + (kHalf * 2 + kk) * 16 + l15) * 64 + c * 32 + quad * 8);
  __syncthreads();

  int p = 0, s = 0;
  for (int kb = 0; kb < Cc; kb += 64) {
    if (kb + 64 < Cc) {
      // VT prefetch into 1-p (async, overlaps both MFMA stages)
#pragma unroll
      for (int j = 0; j < 4; j++) {
        int f = (wid * 4 + j) * 64 + lane;
        int row = f >> 3, sc = (f & 7) ^ (row & 7);
        async16(VTb + (size_t)row * Cc + kb + 64 + sc * 8, &VTs[1 - p][f * 8]);
      }
      // S^T(kb+64) -> Ps[1-s]  (kA currently holds keys of kb+64)
#pragma unroll
      for (int kk = 0; kk < 2; kk++) {
        int kf = kHalf * 2 + kk;
#pragma unroll
        for (int qq = 0; qq < 4; qq++) {
          floatx4 d = (floatx4){0.f, 0.f, 0.f, 0.f};
          d = MFMA_BF16(kA[kk][0], qB[qq][0], d);
          d = MFMA_BF16(kA[kk][1], qB[qq][1], d);
          uint2 pk = pack4bf(EXP2F(fmaf(d[0], SC2, mv2[qq])),
                             EXP2F(fmaf(d[1], SC2, mv2[qq])),
                             EXP2F(fmaf(d[2], SC2, mv2[qq])),
                             EXP2F(fmaf(d[3], SC2, mv2[qq])));
          int prow = qHalfS * 64 + qq * 16 + l15;
          *(uint2*)&Ps[1 - s][prow * 64 + (((kf << 1) + (quad >> 1)) ^ l7) * 8 + (quad & 1) * 4] = pk;
        }
      }
      if (kb + 128 < Cc) {   // reload K frags for kb+128
#pragma unroll
        for (int kk = 0; kk < 2; kk++)
#pragma unroll
          for (int c = 0; c < 2; c++)
            kA[kk][c] = *(const short8*)(Kb + (size_t)(kb + 128 + (kHalf * 2 + kk) * 16 + l15) * 64 + c * 32 + quad * 8);
      }
    }

    // PV(kb): wave's 64 q x 64 dv
    short8 pA[4][2];
#pragma unroll
    for (int qq = 0; qq < 4; qq++) {
      int prow = qPV * 64 + qq * 16 + l15;
#pragma unroll
      for (int kc = 0; kc < 2; kc++)
        pA[qq][kc] = *(const short8*)&Ps[s][prow * 64 + (((kc << 2) + quad) ^ l7) * 8];
    }
#pragma unroll
    for (int fn = 0; fn < 4; fn++) {
      int vrow = dvPV * 64 + fn * 16 + l15;
#pragma unroll
      for (int kc = 0; kc < 2; kc++) {
        short8 vB = *(const short8*)&VTs[p][vrow * 64 + (((kc << 2) + quad) ^ l7) * 8];
#pragma unroll
        for (int qq = 0; qq < 4; qq++)
          acc[qq][fn] = MFMA_BF16(pA[qq][kc], vB, acc[qq][fn]);
      }
    }
    __syncthreads();
    p ^= 1; s ^= 1;
  }

#pragma unroll
  for (int qq = 0; qq < 4; qq++)
#pragma unroll
    for (int fn = 0; fn < 4; fn++)
#pragma unroll
      for (int r = 0; r < 4; r++) {
        int q = qt + qPV * 64 + qq * 16 + quad * 4 + r;
        int dv = dvPV * 64 + fn * 16 + l15;
        Ab[((size_t)bh * Cc + q) * 128 + dv] = f2bf(acc[qq][fn][r]);
      }
}

// ---------------------------------------------------------------------------
extern "C" void kernel_launch(void* const* d_in, const int* in_sizes, int n_in,
                              void* d_out, int out_size, void* d_ws, size_t ws_size,
                              hipStream_t stream)
{
  const float* x    = (const float*)d_in[0];
  const float* mask = (const float*)d_in[1];
  const float* Mq_w = (const float*)d_in[2];
  const float* Mq_b = (const float*)d_in[3];
  const float* Mk_w = (const float*)d_in[4];
  const float* Mk_b = (const float*)d_in[5];
  const float* Mv_w = (const float*)d_in[6];
  const float* Mv_b = (const float*)d_in[7];
  const float* Wo_w = (const float*)d_in[8];
  const float* Wo_b = (const float*)d_in[9];
  float* outp = (float*)d_out;

  us* xb  = (us*)d_ws;
  us* wq  = xb  + 8388608;     // x:    8192x1024
  us* wk  = wq  + 524288;      // Mq_w: 512x1024   (wq|wk|wv contiguous = Wall)
  us* wv  = wk  + 524288;
  us* wo  = wv  + 1048576;     // Mv_w: 1024x1024
  us* Qb  = wo  + 1048576;     // Wo_w: 1024x1024
  us* Kb  = Qb  + 4194304;     // Q:    8192x512
  us* Vb  = Kb  + 4194304;
  us* VTb = Vb  + 8388608;     // V:    8192x1024
  us* Ab  = VTb + 8388608;     // VT:   32x128x2048
  float* invZ = (float*)(Ab + 8388608);   // 32x2048 fp32

  cast_all<<<5632, 256, 0, stream>>>(x, Mq_w, Mk_w, Mv_w, Wo_w, xb, wq, wk, wv, wo);

  gemm_qkv<<<1024, 256, 0, stream>>>(xb, wq, Mq_b, Mk_b, Mv_b, Qb, Kb, Vb);

  attn_pass1<<<512, 256, 0, stream>>>(Qb, Kb, mask, invZ);
  transpose_v<<<dim3(64, 32), 256, 0, stream>>>(Vb, invZ, VTb);
  attn_pass2<<<512, 256, 0, stream>>>(Qb, Kb, VTb, mask, Ab);

  gemm_out<<<512, 256, 0, stream>>>(Ab, wo, Wo_b, outp);
}